// Round 2
// baseline (1276.717 us; speedup 1.0000x reference)
//
#include <hip/hip_runtime.h>
#include <hip/hip_bf16.h>

// GroupedExperts: out = (silu(x@gate) * (x@down)) @ up  per expert.
// E=8, T=4096, D_IN=2048, D_H=1408. fp32 in/out (per reference),
// bf16 MFMA compute internally (threshold is 2% of max|ref| => bf16-tolerant).

typedef __bf16 bf16x8 __attribute__((ext_vector_type(8)));
typedef float  f32x4  __attribute__((ext_vector_type(4)));

__device__ __forceinline__ void gload16(const void* g, void* l) {
  // async global->LDS, 16B per lane; LDS dest = wave-uniform base + lane*16
  __builtin_amdgcn_global_load_lds((const __attribute__((address_space(1))) void*)g,
                                   (__attribute__((address_space(3))) void*)l,
                                   16, 0, 0);
}

__device__ __forceinline__ unsigned short f2bf(float f) {
  union { float fv; unsigned u; } v; v.fv = f;
  unsigned r = (v.u + 0x7fffu + ((v.u >> 16) & 1u)) >> 16;  // RNE
  return (unsigned short)r;
}

// ------------- cast fp32 -> bf16, flat, vectorized -------------------------
__global__ __launch_bounds__(256)
void cvt_f32_bf16(const float* __restrict__ in, unsigned short* __restrict__ out,
                  long n) {
  long i = ((long)blockIdx.x * 256 + threadIdx.x) * 4;
  const long stride = (long)gridDim.x * 1024;
  for (; i < n; i += stride) {
    const float4 v = *(const float4*)(in + i);
    ushort4 o;
    o.x = f2bf(v.x); o.y = f2bf(v.y); o.z = f2bf(v.z); o.w = f2bf(v.w);
    *(ushort4*)(out + i) = o;
  }
}

// ------------- transpose+cast: fp32 [E][R][C] -> bf16 [E][C][R] ------------
__global__ __launch_bounds__(256)
void trcvt(const float* __restrict__ in, unsigned short* __restrict__ out,
           int R, int C) {
  __shared__ unsigned short tile[32][33];
  const float* src = in + (size_t)blockIdx.z * R * C;
  unsigned short* dst = out + (size_t)blockIdx.z * R * C;
  const int c0 = blockIdx.x << 5, r0 = blockIdx.y << 5;
  const int tx = threadIdx.x, ty = threadIdx.y;  // block (32,8)
#pragma unroll
  for (int i = 0; i < 32; i += 8)
    tile[ty + i][tx] = f2bf(src[(size_t)(r0 + ty + i) * C + (c0 + tx)]);
  __syncthreads();
#pragma unroll
  for (int i = 0; i < 32; i += 8)
    dst[(size_t)(c0 + ty + i) * R + (r0 + tx)] = tile[tx][ty + i];
}

// ---------------- m97-style GEMM: C[4096][NDIM] = A[4096][KDIM] @ B^T ------
// A, B0, B1 bf16; B pre-transposed [NDIM][KDIM]. FUSED: C = silu(A@B0)*(A@B1).
// F32OUT: write fp32 C, else bf16. 128x128 tile, BK=32, 256 threads (4 waves,
// each a 64x64 quadrant of 4x4 16x16x32 MFMAs). LDS 16B-chunk XOR swizzle
// (kslot = kchunk ^ ((row>>1)&3)) kills the 8-way ds_read_b128 conflict of the
// unpadded [row][32] layout; global_load_lds lane addresses permuted to match.
template <int KDIM, int NDIM, bool FUSED, bool F32OUT, int MINW>
__global__ __launch_bounds__(256, MINW)
void gemm_bt(const unsigned short* __restrict__ A,
             const unsigned short* __restrict__ B0,
             const unsigned short* __restrict__ B1,
             void* __restrict__ Cout) {
  __shared__ __align__(16) unsigned short sA[128 * 32];
  __shared__ __align__(16) unsigned short sB0[128 * 32];
  __shared__ __align__(16) unsigned short sB1[FUSED ? 128 * 32 : 8];

  const int t = threadIdx.x;
  const int w = t >> 6;
  const int lane = t & 63;
  const int e = blockIdx.z;
  const int m0 = blockIdx.y << 7;
  const int n0 = blockIdx.x << 7;

  const unsigned short* Ae  = A  + (size_t)e * 4096 * KDIM;
  const unsigned short* B0e = B0 + (size_t)e * NDIM * KDIM;
  const unsigned short* B1e = nullptr;
  if (FUSED) B1e = B1 + (size_t)e * NDIM * KDIM;

  // staging: 8 chunks of 1024B per 128x32 tile; wave w does chunks 2w, 2w+1.
  // lane l of chunk c lands at LDS row c*16 + l/4, 16B-slot l&3; it must fetch
  // global k-chunk (l&3) ^ ((l>>3)&3)  [= kslot ^ ((rowlocal>>1)&3)].
  const int srow  = lane >> 2;
  const int selem = ((lane & 3) ^ ((lane >> 3) & 3)) * 8;
  const unsigned short* aSrc[2];
  const unsigned short* b0Src[2];
  const unsigned short* b1Src[2];
  unsigned short *aDst[2], *b0Dst[2], *b1Dst[2];
#pragma unroll
  for (int i = 0; i < 2; ++i) {
    const int c = 2 * w + i;
    aSrc[i]  = Ae  + (size_t)(m0 + c * 16 + srow) * KDIM + selem;
    b0Src[i] = B0e + (size_t)(n0 + c * 16 + srow) * KDIM + selem;
    aDst[i]  = &sA[c * 512];
    b0Dst[i] = &sB0[c * 512];
    if (FUSED) {
      b1Src[i] = B1e + (size_t)(n0 + c * 16 + srow) * KDIM + selem;
      b1Dst[i] = &sB1[c * 512];
    }
  }

  f32x4 acc0[4][4], acc1[4][4];
  const f32x4 z = {0.f, 0.f, 0.f, 0.f};
#pragma unroll
  for (int mi = 0; mi < 4; ++mi)
#pragma unroll
    for (int ni = 0; ni < 4; ++ni) { acc0[mi][ni] = z; acc1[mi][ni] = z; }

  const bf16x8* pA  = (const bf16x8*)sA;
  const bf16x8* pB0 = (const bf16x8*)sB0;
  const bf16x8* pB1 = (const bf16x8*)sB1;
  const int wm = (w >> 1) << 6;
  const int wn = (w & 1) << 6;
  const int lm = lane & 15;
  const int kq = lane >> 4;
  const int ksw = kq ^ ((lm >> 1) & 3);  // swizzle-consistent fragment slot
  const int fa = (wm + lm) * 4 + ksw;
  const int fb = (wn + lm) * 4 + ksw;

  for (int kk = 0; kk < KDIM / 32; ++kk) {
    __syncthreads();  // previous tile's compute done before overwrite
#pragma unroll
    for (int i = 0; i < 2; ++i) {
      gload16(aSrc[i],  aDst[i]);   aSrc[i]  += 32;
      gload16(b0Src[i], b0Dst[i]);  b0Src[i] += 32;
      if (FUSED) { gload16(b1Src[i], b1Dst[i]); b1Src[i] += 32; }
    }
    __syncthreads();  // compiler drains vmcnt(0) here -> tiles visible

    bf16x8 af[4], bf0[4], bf1[4];
#pragma unroll
    for (int mi = 0; mi < 4; ++mi) af[mi] = pA[fa + (mi << 6)];
#pragma unroll
    for (int ni = 0; ni < 4; ++ni) {
      bf0[ni] = pB0[fb + (ni << 6)];
      if (FUSED) bf1[ni] = pB1[fb + (ni << 6)];
    }
#pragma unroll
    for (int mi = 0; mi < 4; ++mi)
#pragma unroll
      for (int ni = 0; ni < 4; ++ni) {
        acc0[mi][ni] = __builtin_amdgcn_mfma_f32_16x16x32_bf16(af[mi], bf0[ni], acc0[mi][ni], 0, 0, 0);
        if (FUSED)
          acc1[mi][ni] = __builtin_amdgcn_mfma_f32_16x16x32_bf16(af[mi], bf1[ni], acc1[mi][ni], 0, 0, 0);
      }
  }

  // epilogue: C/D layout col=lane&15, row=(lane>>4)*4+reg (m89-verified)
#pragma unroll
  for (int mi = 0; mi < 4; ++mi)
#pragma unroll
    for (int ni = 0; ni < 4; ++ni)
#pragma unroll
      for (int i = 0; i < 4; ++i) {
        const int row = m0 + wm + (mi << 4) + (kq << 2) + i;
        const int col = n0 + wn + (ni << 4) + lm;
        float v = acc0[mi][ni][i];
        if (FUSED) {
          const float g = v;
          const float d = acc1[mi][ni][i];
          v = g / (1.0f + __expf(-g)) * d;  // silu(g)*d
        }
        const size_t idx = (size_t)e * 4096 * NDIM + (size_t)row * NDIM + col;
        if (F32OUT) ((float*)Cout)[idx] = v;
        else        ((unsigned short*)Cout)[idx] = f2bf(v);
      }
}

extern "C" void kernel_launch(void* const* d_in, const int* in_sizes, int n_in,
                              void* d_out, int out_size, void* d_ws, size_t ws_size,
                              hipStream_t stream) {
  const float* x    = (const float*)d_in[0];  // [8][4096][2048] fp32
  const float* gate = (const float*)d_in[1];  // [8][2048][1408] fp32
  const float* down = (const float*)d_in[2];  // [8][2048][1408] fp32
  const float* up   = (const float*)d_in[3];  // [8][1408][2048] fp32

  // d_out doubles as scratch for x_bf16 (134 MB < 268 MB out buffer);
  // GEMM2 overwrites it with the final fp32 result (stream-ordered, and
  // GEMM2 never reads d_out).
  unsigned short* xb = (unsigned short*)d_out;

  char* ws = (char*)d_ws;
  unsigned short* h    = (unsigned short*)ws;                   // 92,274,688 B
  unsigned short* bufG = (unsigned short*)(ws + 92274688ull);   // 46,137,344 B (gate^T, then up^T)
  unsigned short* bufD = (unsigned short*)(ws + 138412032ull);  // 46,137,344 B (down^T)
  // total ws need: 184,549,376 B

  const long nx = 8L * 4096 * 2048;
  cvt_f32_bf16<<<8192, 256, 0, stream>>>(x, xb, nx);

  dim3 tb(32, 8, 1);
  // gate/down: fp32 [2048][1408] -> bf16 [1408][2048]
  trcvt<<<dim3(44, 64, 8), tb, 0, stream>>>(gate, bufG, 2048, 1408);
  trcvt<<<dim3(44, 64, 8), tb, 0, stream>>>(down, bufD, 2048, 1408);
  // h = silu(x@gate) * (x@down):  M=4096, N=1408, K=2048, bf16 out
  gemm_bt<2048, 1408, true, false, 2><<<dim3(11, 32, 8), 256, 0, stream>>>(xb, bufG, bufD, h);
  // up: fp32 [1408][2048] -> bf16 [2048][1408]  (reuses bufG)
  trcvt<<<dim3(64, 44, 8), tb, 0, stream>>>(up, bufG, 1408, 2048);
  // out = h @ up:  M=4096, N=2048, K=1408, fp32 out
  gemm_bt<1408, 2048, false, true, 3><<<dim3(16, 32, 8), 256, 0, stream>>>(h, bufG, nullptr, (float*)d_out);
}